// Round 1
// baseline (90.389 us; speedup 1.0000x reference)
//
#include <hip/hip_runtime.h>
#include <math.h>

#define PH 7
#define PW 7
#define BB 4
#define HH 64
#define WW 64
#define CC 256
#define RR 128
#define CH4 (CC / 4)                   // 64 float4 per pixel
#define BINS_PER_IMG (RR * PH * PW)    // 6272
#define NBINS (BB * BINS_PER_IMG)      // 25088
#define WPB 2                          // waves per block (128 threads)
#define NBLK (NBINS / WPB)             // 12544 blocks
#define BLK_PER_SLOT (NBLK / 8)        // 1568 per xcd slot

typedef float f4 __attribute__((ext_vector_type(4)));

__device__ __forceinline__ f4 max4(f4 a, f4 b) {
    f4 r;
    r.x = fmaxf(a.x, b.x); r.y = fmaxf(a.y, b.y);
    r.z = fmaxf(a.z, b.z); r.w = fmaxf(a.w, b.w);
    return r;
}

// One wave per output bin (TLP: 25088 waves). v2 changes vs 88.5us baseline:
//  - ping-pong prefetch (bufA/bufB, statically indexed): round t+1's 8 loads
//    issue BEFORE round t's consume -> 8-16 loads continuously in flight,
//    compiler emits incremental vmcnt(15..8) instead of a per-round drain.
//  - 128-thread blocks (2 waves): halves straggler coupling (corner bins run
//    up to 16 rounds vs avg ~2.4) and doubles dispatch granularity.
//  - wave-uniform SGPR base + 32-bit per-lane index (bp[idx + lane]) to cut
//    64-bit address VALU per pixel; tree-max consume (dep chain 8 -> 3).
// Lane l = channels 4l..4l+3 -> each pixel load is a 1KB coalesced wave
// transaction. Flat pixel index p -> (row,col) in bin via 16-bit magic divide
// (exact: p <= ~120, wbin <= 11). Tail clamp re-loads pixel npix-1: same
// line, L1-hit, idempotent under max. XCD swizzle: image b -> xcds {2b,2b+1}
// keeps its 4.2MB fm slice hot in one L2 pair (R2 evidence: FETCH 50->12MB).
__global__ __launch_bounds__(128) void ROIPoolingLayer_62079457296467_kernel(
    const float* __restrict__ fm, const float* __restrict__ rois,
    float* __restrict__ out)
{
    const int wave = threadIdx.x >> 6;
    const int lane = threadIdx.x & 63;

    // ---- XCD swizzle: 12544 blocks = 8 xcds x 1568; image b -> xcds {2b,2b+1}
    const int bid   = blockIdx.x;
    const int xcd   = bid & 7;
    const int slot  = bid >> 3;                        // 0..1567
    const int b     = xcd >> 1;                        // image 0..3
    const int blkin = (xcd & 1) * BLK_PER_SLOT + slot; // 0..3135 in image
    const int local = blkin * WPB + wave;              // 0..6271 = r*49 + bin
    const int r     = local / (PH * PW);
    const int bin   = local - r * (PH * PW);
    const int ph    = bin / PW;
    const int pw    = bin - ph * PW;
    const int br    = b * RR + r;

    // ---- ROI decode (reference fp32 semantics, truncating casts) ----
    const f4 roi = ((const f4*)rois)[br];
    const int h0 = (int)floorf((float)HH * roi.x);
    const int w0 = (int)floorf((float)WW * roi.y);
    const int h1 = (int)floorf((float)HH * roi.z);
    const int w1 = (int)floorf((float)WW * roi.w);
    const int rh = h1 - h0;
    const int rw = w1 - w0;
    const int hstep = max(rh / PH, 1);
    const int wstep = max(rw / PW, 1);

    // Bin window [hs,he) x [ws,we); last bin extends to region end.
    int hs = h0 + ph * hstep;
    int he = (ph == PH - 1) ? (h0 + rh) : (hs + hstep);
    he = min(he, h0 + rh);  he = min(he, HH);
    int ws = w0 + pw * wstep;
    int we = (pw == PW - 1) ? (w0 + rw) : (ws + wstep);
    we = min(we, w0 + rw);  we = min(we, WW);

    const int hbin = he - hs;
    const int wbin = we - ws;
    const int npix = hbin * wbin;

    // wave-uniform base (stays in SGPRs); per-lane offset is 32-bit
    const f4* __restrict__ bp =
        (const f4*)fm + ((size_t)b * HH + hs) * (WW * CH4) + (size_t)ws * CH4;

    f4 acc = (f4){-INFINITY, -INFINITY, -INFINITY, -INFINITY};

    if (npix > 0) {
        // magic divide by wbin: q = (p*m)>>16 == p/wbin for p*e < 2^16
        const unsigned m = (65536u + (unsigned)wbin - 1) / (unsigned)wbin;
        f4 bufA[8], bufB[8];

#define LOADR(buf, p0)                                                  \
        _Pragma("unroll")                                               \
        for (int k = 0; k < 8; ++k) {                                   \
            const int pk = min((p0) + k, npix - 1);                     \
            const int q  = (int)(((unsigned)pk * m) >> 16);             \
            const int w  = pk - q * wbin;                               \
            buf[k] = bp[(q * WW + w) * CH4 + lane];                     \
        }
#define CONS(buf)                                                       \
        {                                                               \
            f4 m0 = max4(buf[0], buf[1]);                               \
            f4 m1 = max4(buf[2], buf[3]);                               \
            f4 m2 = max4(buf[4], buf[5]);                               \
            f4 m3 = max4(buf[6], buf[7]);                               \
            acc = max4(acc, max4(max4(m0, m1), max4(m2, m3)));          \
        }

        const int rounds = (npix + 7) >> 3;   // <= 16
        LOADR(bufA, 0)
        int t = 1;
        for (; t + 1 < rounds; t += 2) {      // steady state: 16 loads in flight
            LOADR(bufB, t * 8)
            CONS(bufA)
            LOADR(bufA, (t + 1) * 8)
            CONS(bufB)
        }
        if (t < rounds) {                     // even round count: one more pair
            LOADR(bufB, t * 8)
            CONS(bufA)
            CONS(bufB)
        } else {
            CONS(bufA)
        }
#undef LOADR
#undef CONS
    }

    // Output (b,r,ph,pw,C): gbin = b*6272 + local; non-temporal (never re-read).
    const size_t gbin = (size_t)b * BINS_PER_IMG + local;
    __builtin_nontemporal_store(acc, (f4*)out + gbin * CH4 + lane);
}

extern "C" void kernel_launch(void* const* d_in, const int* in_sizes, int n_in,
                              void* d_out, int out_size, void* d_ws, size_t ws_size,
                              hipStream_t stream) {
    const float* fm   = (const float*)d_in[0];
    const float* rois = (const float*)d_in[1];
    float* out        = (float*)d_out;
    ROIPoolingLayer_62079457296467_kernel<<<NBLK, 128, 0, stream>>>(fm, rois, out);
}